// Round 1
// baseline (49.680 us; speedup 1.0000x reference)
//
#include <hip/hip_runtime.h>
#include <math.h>

#define Gg 64
#define Ll 4096
#define Ss 65536
#define Nn (Gg * Ll)            // 262144 rows
#define K_CHUNKS 32             // blocks per group
#define PAIR_BLOCKS (Gg * K_CHUNKS)       // 2048 blocks
#define PAIRS_PER_BLOCK (Ss / K_CHUNKS)   // 2048 pairs per block
#define BLOCK 256

// ---------------------------------------------------------------------------
// Kernel 1: compact CA rows of inputs & target into a 32B-aligned row each:
//   comb[i] = { in.x, in.y, in.z, tg.x, tg.y, tg.z, 0, 0 }   (8 floats)
// Source row i's CA atom lives at flat offset i*9 + 3 .. i*9 + 5.
// ---------------------------------------------------------------------------
__global__ __launch_bounds__(BLOCK) void compact_kernel(
    const float* __restrict__ inp, const float* __restrict__ tgt,
    float* __restrict__ comb) {
  int i = blockIdx.x * BLOCK + threadIdx.x;
  if (i >= Nn) return;
  const float* a = inp + (size_t)i * 9 + 3;
  const float* b = tgt + (size_t)i * 9 + 3;
  float4 r0 = make_float4(a[0], a[1], a[2], b[0]);
  float4 r1 = make_float4(b[1], b[2], 0.f, 0.f);
  float4* o = (float4*)(comb + (size_t)i * 8);
  o[0] = r0;
  o[1] = r1;
}

// ---------------------------------------------------------------------------
// Kernel 2: pair gather + per-block partial sum.
// XCD-aware mapping: bid%8 selects the XCD (default round-robin dispatch);
// all K_CHUNKS blocks of a group share one XCD so the group's 128KB comb
// slice stays resident in that XCD's L2.
// ---------------------------------------------------------------------------
template <typename IT>
__global__ __launch_bounds__(BLOCK) void pair_kernel(
    const float* __restrict__ comb,
    const IT* __restrict__ left, const IT* __restrict__ right,
    float* __restrict__ partial) {
  int bid = blockIdx.x;
  int x = bid & 7;          // target XCD
  int j = bid >> 3;
  int group = x + 8 * (j / K_CHUNKS);   // groups {x, x+8, ..., x+56} on XCD x
  int chunk = j % K_CHUNKS;
  size_t base = (size_t)group * Ss + (size_t)chunk * PAIRS_PER_BLOCK;

  float acc = 0.f;
#pragma unroll 2
  for (int t = threadIdx.x; t < PAIRS_PER_BLOCK; t += BLOCK) {
    size_t p = base + t;
    size_t li = (size_t)left[p];
    size_t ri = (size_t)right[p];
    const float* lrow = comb + li * 8;
    const float* rrow = comb + ri * 8;
    float4 l0 = *(const float4*)(lrow);
    float2 l1 = *(const float2*)(lrow + 4);
    float4 r0 = *(const float4*)(rrow);
    float2 r1 = *(const float2*)(rrow + 4);
    float dx = l0.x - r0.x, dy = l0.y - r0.y, dz = l0.z - r0.z;
    float tx = l0.w - r0.w, ty = l1.x - r1.x, tz = l1.y - r1.y;
    float din = sqrtf(dx * dx + dy * dy + dz * dz);
    float dtg = sqrtf(tx * tx + ty * ty + tz * tz);
    float d = din - dtg;
    acc += d * d;
  }

  // wave reduce (64 lanes) then cross-wave via LDS
  for (int off = 32; off; off >>= 1) acc += __shfl_down(acc, off, 64);
  __shared__ float wsum[BLOCK / 64];
  if ((threadIdx.x & 63) == 0) wsum[threadIdx.x >> 6] = acc;
  __syncthreads();
  if (threadIdx.x == 0) {
    float s = 0.f;
    for (int w = 0; w < BLOCK / 64; ++w) s += wsum[w];
    partial[bid] = s;
  }
}

// ---------------------------------------------------------------------------
// Fallback (no comb buffer): gather 3 scalars per tensor per side directly.
// ---------------------------------------------------------------------------
template <typename IT>
__global__ __launch_bounds__(BLOCK) void pair_kernel_direct(
    const float* __restrict__ inp, const float* __restrict__ tgt,
    const IT* __restrict__ left, const IT* __restrict__ right,
    float* __restrict__ partial) {
  int bid = blockIdx.x;
  int x = bid & 7;
  int j = bid >> 3;
  int group = x + 8 * (j / K_CHUNKS);
  int chunk = j % K_CHUNKS;
  size_t base = (size_t)group * Ss + (size_t)chunk * PAIRS_PER_BLOCK;

  float acc = 0.f;
  for (int t = threadIdx.x; t < PAIRS_PER_BLOCK; t += BLOCK) {
    size_t p = base + t;
    size_t li = (size_t)left[p] * 9 + 3;
    size_t ri = (size_t)right[p] * 9 + 3;
    float dx = inp[li + 0] - inp[ri + 0];
    float dy = inp[li + 1] - inp[ri + 1];
    float dz = inp[li + 2] - inp[ri + 2];
    float tx = tgt[li + 0] - tgt[ri + 0];
    float ty = tgt[li + 1] - tgt[ri + 1];
    float tz = tgt[li + 2] - tgt[ri + 2];
    float din = sqrtf(dx * dx + dy * dy + dz * dz);
    float dtg = sqrtf(tx * tx + ty * ty + tz * tz);
    float d = din - dtg;
    acc += d * d;
  }

  for (int off = 32; off; off >>= 1) acc += __shfl_down(acc, off, 64);
  __shared__ float wsum[BLOCK / 64];
  if ((threadIdx.x & 63) == 0) wsum[threadIdx.x >> 6] = acc;
  __syncthreads();
  if (threadIdx.x == 0) {
    float s = 0.f;
    for (int w = 0; w < BLOCK / 64; ++w) s += wsum[w];
    partial[bid] = s;
  }
}

// ---------------------------------------------------------------------------
// Kernel 3: deterministic final reduce of PAIR_BLOCKS partials, fp64 accum.
// ---------------------------------------------------------------------------
__global__ __launch_bounds__(BLOCK) void reduce_kernel(
    const float* __restrict__ partial, float* __restrict__ out) {
  double acc = 0.0;
  for (int i = threadIdx.x; i < PAIR_BLOCKS; i += BLOCK)
    acc += (double)partial[i];
  for (int off = 32; off; off >>= 1) acc += __shfl_down(acc, off, 64);
  __shared__ double wsum[BLOCK / 64];
  if ((threadIdx.x & 63) == 0) wsum[threadIdx.x >> 6] = acc;
  __syncthreads();
  if (threadIdx.x == 0) {
    double s = 0.0;
    for (int w = 0; w < BLOCK / 64; ++w) s += wsum[w];
    out[0] = (float)(s / (double)((size_t)Gg * Ss));
  }
}

extern "C" void kernel_launch(void* const* d_in, const int* in_sizes, int n_in,
                              void* d_out, int out_size, void* d_ws, size_t ws_size,
                              hipStream_t stream) {
  const float* inp = (const float*)d_in[0];   // (N,3,3) f32
  const float* tgt = (const float*)d_in[1];   // (N,3,3) f32
  // d_in[2] = mask (unused by reference)
  const void* leftp = d_in[3];
  const void* rightp = d_in[4];
  float* out = (float*)d_out;

  // Index dtype: harness normally passes int32; detect int64 passthrough
  // (flat element count doubled) just in case.
  const bool idx64 = (in_sizes[3] == 2 * (int)((size_t)Gg * Ss / 1));
  // note: Gg*Ss = 4194304 fits in int.

  size_t combBytes = (size_t)Nn * 8 * sizeof(float);
  size_t partBytes = (size_t)PAIR_BLOCKS * sizeof(float);

  if (ws_size >= combBytes + partBytes) {
    float* comb = (float*)d_ws;
    float* partial = (float*)((char*)d_ws + combBytes);
    compact_kernel<<<Nn / BLOCK, BLOCK, 0, stream>>>(inp, tgt, comb);
    if (idx64) {
      pair_kernel<long long><<<PAIR_BLOCKS, BLOCK, 0, stream>>>(
          comb, (const long long*)leftp, (const long long*)rightp, partial);
    } else {
      pair_kernel<int><<<PAIR_BLOCKS, BLOCK, 0, stream>>>(
          comb, (const int*)leftp, (const int*)rightp, partial);
    }
    reduce_kernel<<<1, BLOCK, 0, stream>>>(partial, out);
  } else {
    // fallback: no comb buffer, direct gathers
    float* partial = (float*)d_ws;
    if (idx64) {
      pair_kernel_direct<long long><<<PAIR_BLOCKS, BLOCK, 0, stream>>>(
          inp, tgt, (const long long*)leftp, (const long long*)rightp, partial);
    } else {
      pair_kernel_direct<int><<<PAIR_BLOCKS, BLOCK, 0, stream>>>(
          inp, tgt, (const int*)leftp, (const int*)rightp, partial);
    }
    reduce_kernel<<<1, BLOCK, 0, stream>>>(partial, out);
  }
}

// Round 2
// 21.940 us; speedup vs baseline: 2.2643x; 2.2643x over previous
//
#include <hip/hip_runtime.h>
#include <math.h>

#define Gg 64
#define Ll 4096
#define Ss 65536
#define Nn (Gg * Ll)                      // 262144 rows
#define PAIR_BLOCK 1024
#define CHUNKS 8                          // blocks per group
#define PAIR_BLOCKS (Gg * CHUNKS)         // 512
#define PAIRS_PER_BLOCK (Ss / CHUNKS)     // 8192
#define ITERS (PAIRS_PER_BLOCK / PAIR_BLOCK)  // 8

// fallback path constants (direct f32 gather, no workspace)
#define K_CHUNKS 32
#define DIR_BLOCKS (Gg * K_CHUNKS)        // 2048
#define DIR_PAIRS (Ss / K_CHUNKS)         // 2048
#define BLOCK 256

typedef _Float16 h2 __attribute__((ext_vector_type(2)));
typedef _Float16 h8 __attribute__((ext_vector_type(8)));

__device__ inline float dot2f16(h2 a, h2 b, float c) {
#if __has_builtin(__builtin_amdgcn_fdot2)
  return __builtin_amdgcn_fdot2(a, b, c, false);
#else
  return fmaf((float)a[0], (float)b[0], fmaf((float)a[1], (float)b[1], c));
#endif
}

// ---------------------------------------------------------------------------
// Kernel 1: compact CA rows of inputs & target into one 16B fp16 row:
//   row[i] = { in.x, in.y, tg.x, tg.y, in.z, tg.z, 0, 0 }  (8 half)
// Source CA atom of row i is flat floats [i*9+3 .. i*9+5].
// ---------------------------------------------------------------------------
__global__ __launch_bounds__(BLOCK) void compact16_kernel(
    const float* __restrict__ inp, const float* __restrict__ tgt,
    h8* __restrict__ comb) {
  int i = blockIdx.x * BLOCK + threadIdx.x;
  if (i >= Nn) return;
  const float* a = inp + (size_t)i * 9 + 3;
  const float* b = tgt + (size_t)i * 9 + 3;
  h8 row;
  row[0] = (_Float16)a[0];
  row[1] = (_Float16)a[1];
  row[2] = (_Float16)b[0];
  row[3] = (_Float16)b[1];
  row[4] = (_Float16)a[2];
  row[5] = (_Float16)b[2];
  row[6] = (_Float16)0.f;
  row[7] = (_Float16)0.f;
  comb[i] = row;
}

// ---------------------------------------------------------------------------
// Kernel 2: LDS-staged pair gather.
// Each block stages its group's full 64KB fp16 slice into LDS, then gathers
// pairs from LDS (2 x ds_read_b128 per pair) instead of the global/L1 path.
// XCD-aware mapping: bid%8 = XCD; all 8 chunks of a group land on one XCD.
// 2 blocks/CU co-resident (128KB LDS), 32 waves/CU.
// ---------------------------------------------------------------------------
template <typename IT>
__global__ __launch_bounds__(PAIR_BLOCK) void pair16_kernel(
    const h8* __restrict__ comb,
    const IT* __restrict__ left, const IT* __restrict__ right,
    float* __restrict__ partial) {
  __shared__ h8 tile[Ll];   // 64 KB

  int bid = blockIdx.x;
  int xcd = bid & 7;
  int j = bid >> 3;
  int gi = j & 7;
  int chunk = j >> 3;
  int group = xcd * 8 + gi;

  // stage group slice: 4096 rows x 16B, fully coalesced
  const h8* src = comb + (size_t)group * Ll;
  for (int k = threadIdx.x; k < Ll; k += PAIR_BLOCK) tile[k] = src[k];
  __syncthreads();

  size_t base = (size_t)group * Ss + (size_t)chunk * PAIRS_PER_BLOCK;
  float acc = 0.f;
#pragma unroll
  for (int t = 0; t < ITERS; ++t) {
    size_t p = base + (size_t)t * PAIR_BLOCK + threadIdx.x;
    int li = (int)left[p] & (Ll - 1);   // group-local row
    int ri = (int)right[p] & (Ll - 1);
    h8 L = tile[li];
    h8 R = tile[ri];
    h8 D = L - R;                       // 4 x v_pk_add_f16 (pad lanes harmless)
    h2 d01 = __builtin_shufflevector(D, D, 0, 1);  // (dx_in, dy_in)
    h2 d23 = __builtin_shufflevector(D, D, 2, 3);  // (dx_tg, dy_tg)
    float dzi = (float)D[4];
    float dzt = (float)D[5];
    float din2 = dot2f16(d01, d01, dzi * dzi);
    float dtg2 = dot2f16(d23, d23, dzt * dzt);
    float d = sqrtf(din2) - sqrtf(dtg2);
    acc = fmaf(d, d, acc);
  }

  // wave reduce then cross-wave via LDS
  for (int off = 32; off; off >>= 1) acc += __shfl_down(acc, off, 64);
  __shared__ float wsum[PAIR_BLOCK / 64];
  if ((threadIdx.x & 63) == 0) wsum[threadIdx.x >> 6] = acc;
  __syncthreads();
  if (threadIdx.x == 0) {
    float s = 0.f;
    for (int w = 0; w < PAIR_BLOCK / 64; ++w) s += wsum[w];
    partial[bid] = s;
  }
}

// ---------------------------------------------------------------------------
// Fallback (tiny workspace): direct f32 gathers from inputs/target.
// ---------------------------------------------------------------------------
template <typename IT>
__global__ __launch_bounds__(BLOCK) void pair_kernel_direct(
    const float* __restrict__ inp, const float* __restrict__ tgt,
    const IT* __restrict__ left, const IT* __restrict__ right,
    float* __restrict__ partial) {
  int bid = blockIdx.x;
  int x = bid & 7;
  int j = bid >> 3;
  int group = x + 8 * (j / K_CHUNKS);
  int chunk = j % K_CHUNKS;
  size_t base = (size_t)group * Ss + (size_t)chunk * DIR_PAIRS;

  float acc = 0.f;
  for (int t = threadIdx.x; t < DIR_PAIRS; t += BLOCK) {
    size_t p = base + t;
    size_t li = (size_t)left[p] * 9 + 3;
    size_t ri = (size_t)right[p] * 9 + 3;
    float dx = inp[li + 0] - inp[ri + 0];
    float dy = inp[li + 1] - inp[ri + 1];
    float dz = inp[li + 2] - inp[ri + 2];
    float tx = tgt[li + 0] - tgt[ri + 0];
    float ty = tgt[li + 1] - tgt[ri + 1];
    float tz = tgt[li + 2] - tgt[ri + 2];
    float din = sqrtf(dx * dx + dy * dy + dz * dz);
    float dtg = sqrtf(tx * tx + ty * ty + tz * tz);
    float d = din - dtg;
    acc += d * d;
  }

  for (int off = 32; off; off >>= 1) acc += __shfl_down(acc, off, 64);
  __shared__ float wsum[BLOCK / 64];
  if ((threadIdx.x & 63) == 0) wsum[threadIdx.x >> 6] = acc;
  __syncthreads();
  if (threadIdx.x == 0) {
    float s = 0.f;
    for (int w = 0; w < BLOCK / 64; ++w) s += wsum[w];
    partial[bid] = s;
  }
}

// ---------------------------------------------------------------------------
// Kernel 3: deterministic final reduce, fp64 accumulation.
// ---------------------------------------------------------------------------
__global__ __launch_bounds__(BLOCK) void reduce_kernel(
    const float* __restrict__ partial, int n, float* __restrict__ out) {
  double acc = 0.0;
  for (int i = threadIdx.x; i < n; i += BLOCK)
    acc += (double)partial[i];
  for (int off = 32; off; off >>= 1) acc += __shfl_down(acc, off, 64);
  __shared__ double wsum[BLOCK / 64];
  if ((threadIdx.x & 63) == 0) wsum[threadIdx.x >> 6] = acc;
  __syncthreads();
  if (threadIdx.x == 0) {
    double s = 0.0;
    for (int w = 0; w < BLOCK / 64; ++w) s += wsum[w];
    out[0] = (float)(s / (double)((size_t)Gg * Ss));
  }
}

extern "C" void kernel_launch(void* const* d_in, const int* in_sizes, int n_in,
                              void* d_out, int out_size, void* d_ws, size_t ws_size,
                              hipStream_t stream) {
  const float* inp = (const float*)d_in[0];   // (N,3,3) f32
  const float* tgt = (const float*)d_in[1];   // (N,3,3) f32
  // d_in[2] = mask (unused by the reference)
  const void* leftp = d_in[3];
  const void* rightp = d_in[4];
  float* out = (float*)d_out;

  const int P = Gg * Ss;                       // 4194304, fits in int
  const bool idx64 = (in_sizes[3] == 2 * P);   // int64 passthrough guard

  size_t combBytes = (size_t)Nn * sizeof(h8);  // 4 MiB
  size_t partBytes = (size_t)DIR_BLOCKS * sizeof(float);

  if (ws_size >= combBytes + partBytes) {
    h8* comb = (h8*)d_ws;
    float* partial = (float*)((char*)d_ws + combBytes);
    compact16_kernel<<<Nn / BLOCK, BLOCK, 0, stream>>>(inp, tgt, comb);
    if (idx64) {
      pair16_kernel<long long><<<PAIR_BLOCKS, PAIR_BLOCK, 0, stream>>>(
          comb, (const long long*)leftp, (const long long*)rightp, partial);
    } else {
      pair16_kernel<int><<<PAIR_BLOCKS, PAIR_BLOCK, 0, stream>>>(
          comb, (const int*)leftp, (const int*)rightp, partial);
    }
    reduce_kernel<<<1, BLOCK, 0, stream>>>(partial, PAIR_BLOCKS, out);
  } else {
    float* partial = (float*)d_ws;
    if (idx64) {
      pair_kernel_direct<long long><<<DIR_BLOCKS, BLOCK, 0, stream>>>(
          inp, tgt, (const long long*)leftp, (const long long*)rightp, partial);
    } else {
      pair_kernel_direct<int><<<DIR_BLOCKS, BLOCK, 0, stream>>>(
          inp, tgt, (const int*)leftp, (const int*)rightp, partial);
    }
    reduce_kernel<<<1, BLOCK, 0, stream>>>(partial, DIR_BLOCKS, out);
  }
}